// Round 1
// baseline (699.451 us; speedup 1.0000x reference)
//
#include <hip/hip_runtime.h>
#include <hip/hip_bf16.h>

// Problem constants (fixed by setup_inputs)
#define B_ 2
#define L_ 256
#define T_ 250
#define D_ 1024
#define NH_ 16
#define DH_ 64
#define CRv_ 16
#define HID_ 64
#define CL_ 16
#define OUT_ 1024
#define MEMROWS_ 64001L   // L*T + 1

// exact gelu: 0.5*x*(1+erf(x/sqrt(2))), erf via A&S 7.1.26 (|err| < 1.5e-7)
__device__ __forceinline__ float gelu_exact(float x) {
    float xs = x * 0.70710678118654752f;
    float ax = fabsf(xs);
    float t  = __frcp_rn(fmaf(0.3275911f, ax, 1.0f));
    float p  = fmaf(1.061405429f, t, -1.453152027f);
    p = fmaf(p, t, 1.421413741f);
    p = fmaf(p, t, -0.284496736f);
    p = fmaf(p, t, 0.254829592f);
    p = p * t;
    float e = __expf(-ax * ax);
    float erfax = fmaf(-p, e, 1.0f);       // 1 - p*e  (erf(|xs|))
    float erfv  = copysignf(erfax, xs);
    float hx = 0.5f * x;
    return fmaf(hx, erfv, hx);             // 0.5x + 0.5x*erf
}

// Stage 1: per (b,t,cl): out_v[nh*64+dh] = MLP_nh( mem[b, (cl*16+cr)*T+t, nh*64+dh] + dim_pe[cr, d] over cr )
// wave -> nh group, lane -> dh  => all global loads coalesced (256B/wave), weights wave-uniform (scalar loads)
__global__ __launch_bounds__(256) void k_stage1(
    const float* __restrict__ mem, const float* __restrict__ dim_pe,
    const float* __restrict__ W1, const float* __restrict__ b1,
    const float* __restrict__ W2, const float* __restrict__ b2,
    float* __restrict__ vbuf)
{
    const int blk = blockIdx.x;            // b*T*CL + t*CL + cl
    const int cl  = blk % CL_;
    const int t   = (blk / CL_) % T_;
    const int b   = blk / (CL_ * T_);
    const int lane = threadIdx.x & 63;
    const int wv = __builtin_amdgcn_readfirstlane((int)(threadIdx.x >> 6)); // 0..3

    const float* membase = mem + (long)b * MEMROWS_ * D_;

#pragma unroll 1
    for (int j = 0; j < 4; ++j) {
        const int nh = wv * 4 + j;
        const int d  = nh * DH_ + lane;
        const float* w1 = W1 + nh * (CRv_ * HID_);

        float pre[HID_];
#pragma unroll
        for (int f = 0; f < HID_; ++f) pre[f] = b1[nh * HID_ + f];

#pragma unroll 4
        for (int cr = 0; cr < CRv_; ++cr) {
            const int l = cl * CRv_ + cr;
            float vv = membase[((long)l * T_ + t) * D_ + d] + dim_pe[cr * D_ + d];
            const float* w1c = w1 + cr * HID_;
#pragma unroll
            for (int f = 0; f < HID_; ++f) pre[f] = fmaf(vv, w1c[f], pre[f]);
        }

        float a0 = 0.f, a1 = 0.f, a2 = 0.f, a3 = 0.f;
#pragma unroll
        for (int f = 0; f < HID_; f += 4) {
            a0 = fmaf(gelu_exact(pre[f + 0]), W2[nh * HID_ + f + 0], a0);
            a1 = fmaf(gelu_exact(pre[f + 1]), W2[nh * HID_ + f + 1], a1);
            a2 = fmaf(gelu_exact(pre[f + 2]), W2[nh * HID_ + f + 2], a2);
            a3 = fmaf(gelu_exact(pre[f + 3]), W2[nh * HID_ + f + 3], a3);
        }
        float acc = b2[nh] + ((a0 + a1) + (a2 + a3));

        vbuf[((long)(b * CL_ + cl) * T_ + t) * D_ + d] = acc;
    }
}

// Stage 2: per (b,cl,tc): out_h[d] = MLP_nh( vbuf[b,cl,t=tc*16+cr,d] over cr ), t>=250 -> nonsense row
__global__ __launch_bounds__(256) void k_stage2(
    const float* __restrict__ vbuf, const float* __restrict__ mem,
    const float* __restrict__ W1, const float* __restrict__ b1,
    const float* __restrict__ W2, const float* __restrict__ b2,
    float* __restrict__ hbuf)
{
    const int blk = blockIdx.x;            // b*256 + cl*16 + tc
    const int tc  = blk & 15;
    const int cl  = (blk >> 4) & 15;
    const int b   = blk >> 8;
    const int lane = threadIdx.x & 63;
    const int wv = __builtin_amdgcn_readfirstlane((int)(threadIdx.x >> 6));

    const float* nonsense = mem + ((long)b * MEMROWS_ + (long)L_ * T_) * D_;
    const float* vb_base  = vbuf + (long)(b * CL_ + cl) * T_ * D_;

#pragma unroll 1
    for (int j = 0; j < 4; ++j) {
        const int nh = wv * 4 + j;
        const int d  = nh * DH_ + lane;
        const float* w1 = W1 + nh * (CRv_ * HID_);

        float pre[HID_];
#pragma unroll
        for (int f = 0; f < HID_; ++f) pre[f] = b1[nh * HID_ + f];

#pragma unroll 4
        for (int cr = 0; cr < CRv_; ++cr) {
            const int t = tc * CRv_ + cr;
            float vv = (t < T_) ? vb_base[(long)t * D_ + d] : nonsense[d];
            const float* w1c = w1 + cr * HID_;
#pragma unroll
            for (int f = 0; f < HID_; ++f) pre[f] = fmaf(vv, w1c[f], pre[f]);
        }

        float a0 = 0.f, a1 = 0.f, a2 = 0.f, a3 = 0.f;
#pragma unroll
        for (int f = 0; f < HID_; f += 4) {
            a0 = fmaf(gelu_exact(pre[f + 0]), W2[nh * HID_ + f + 0], a0);
            a1 = fmaf(gelu_exact(pre[f + 1]), W2[nh * HID_ + f + 1], a1);
            a2 = fmaf(gelu_exact(pre[f + 2]), W2[nh * HID_ + f + 2], a2);
            a3 = fmaf(gelu_exact(pre[f + 3]), W2[nh * HID_ + f + 3], a3);
        }
        float acc = b2[nh] + ((a0 + a1) + (a2 + a3));

        hbuf[(long)((b * CL_ + cl) * 16 + tc) * D_ + d] = acc;
    }
}

// Stage 3: C(512x1024) = H(512x1024) @ projW^T(1024x1024) + bias. Tiled fp32 GEMM.
// BM=32, BN=64, BK=32; 256 blocks, 256 threads, 2x4 micro-tile.
__global__ __launch_bounds__(256) void k_proj(
    const float* __restrict__ H, const float* __restrict__ Wp,
    const float* __restrict__ bias, float* __restrict__ Cout)
{
    constexpr int BM = 32, BN = 64, BK = 32, K = 1024, NCOLB = OUT_ / BN; // 16
    __shared__ float Ht[BM][BK + 1];
    __shared__ float Wt[BN][BK + 1];

    const int bn = blockIdx.x % NCOLB;
    const int bm = blockIdx.x / NCOLB;
    const int tid = threadIdx.x;
    const int tx = tid & 15;     // 16 col groups * 4
    const int ty = tid >> 4;     // 16 row groups * 2
    const int lr = tid >> 3;     // 0..31
    const int lc = (tid & 7) << 2;

    float acc[2][4] = {};

    for (int k0 = 0; k0 < K; k0 += BK) {
        float4 hv  = *(const float4*)(H  + (long)(bm * BM + lr) * K + k0 + lc);
        float4 w0  = *(const float4*)(Wp + (long)(bn * BN + lr) * K + k0 + lc);
        float4 w1v = *(const float4*)(Wp + (long)(bn * BN + 32 + lr) * K + k0 + lc);
        Ht[lr][lc + 0] = hv.x;  Ht[lr][lc + 1] = hv.y;  Ht[lr][lc + 2] = hv.z;  Ht[lr][lc + 3] = hv.w;
        Wt[lr][lc + 0] = w0.x;  Wt[lr][lc + 1] = w0.y;  Wt[lr][lc + 2] = w0.z;  Wt[lr][lc + 3] = w0.w;
        Wt[32 + lr][lc + 0] = w1v.x; Wt[32 + lr][lc + 1] = w1v.y; Wt[32 + lr][lc + 2] = w1v.z; Wt[32 + lr][lc + 3] = w1v.w;
        __syncthreads();

#pragma unroll
        for (int kk = 0; kk < BK; ++kk) {
            float va0 = Ht[ty * 2 + 0][kk];
            float va1 = Ht[ty * 2 + 1][kk];
            float vb0 = Wt[tx * 4 + 0][kk];
            float vb1 = Wt[tx * 4 + 1][kk];
            float vb2 = Wt[tx * 4 + 2][kk];
            float vb3 = Wt[tx * 4 + 3][kk];
            acc[0][0] = fmaf(va0, vb0, acc[0][0]);
            acc[0][1] = fmaf(va0, vb1, acc[0][1]);
            acc[0][2] = fmaf(va0, vb2, acc[0][2]);
            acc[0][3] = fmaf(va0, vb3, acc[0][3]);
            acc[1][0] = fmaf(va1, vb0, acc[1][0]);
            acc[1][1] = fmaf(va1, vb1, acc[1][1]);
            acc[1][2] = fmaf(va1, vb2, acc[1][2]);
            acc[1][3] = fmaf(va1, vb3, acc[1][3]);
        }
        __syncthreads();
    }

#pragma unroll
    for (int i = 0; i < 2; ++i) {
#pragma unroll
        for (int jj = 0; jj < 4; ++jj) {
            int r = bm * BM + ty * 2 + i;
            int c = bn * BN + tx * 4 + jj;
            Cout[(long)r * OUT_ + c] = acc[i][jj] + bias[c];
        }
    }
}

extern "C" void kernel_launch(void* const* d_in, const int* in_sizes, int n_in,
                              void* d_out, int out_size, void* d_ws, size_t ws_size,
                              hipStream_t stream) {
    const float* mem    = (const float*)d_in[0];
    // d_in[1] = lm_emb (only shapes used by reference)
    const float* dim_pe = (const float*)d_in[2];
    const float* vW1    = (const float*)d_in[3];
    const float* vb1    = (const float*)d_in[4];
    const float* vW2    = (const float*)d_in[5];
    const float* vb2    = (const float*)d_in[6];
    const float* hW1    = (const float*)d_in[7];
    const float* hb1    = (const float*)d_in[8];
    const float* hW2    = (const float*)d_in[9];
    const float* hb2    = (const float*)d_in[10];
    const float* projW  = (const float*)d_in[11];
    const float* projb  = (const float*)d_in[12];
    float* out = (float*)d_out;

    float* vbuf = (float*)d_ws;                       // B*CL*T*D = 8,192,000 floats (32 MB)
    float* hbuf = vbuf + (long)B_ * CL_ * T_ * D_;    // B*256*D  =   524,288 floats (2 MB)

    k_stage1<<<B_ * T_ * CL_, 256, 0, stream>>>(mem, dim_pe, vW1, vb1, vW2, vb2, vbuf);
    k_stage2<<<B_ * CL_ * 16, 256, 0, stream>>>(vbuf, mem, hW1, hb1, hW2, hb2, hbuf);
    k_proj<<<(512 / 32) * (OUT_ / 64), 256, 0, stream>>>(hbuf, projW, projb, out);
}

// Round 2
// 412.699 us; speedup vs baseline: 1.6948x; 1.6948x over previous
//
#include <hip/hip_runtime.h>
#include <hip/hip_bf16.h>

#define B_ 2
#define L_ 256
#define T_ 250
#define D_ 1024
#define NH_ 16
#define DH_ 64
#define CRv_ 16
#define HID_ 64
#define CL_ 16
#define OUT_ 1024
#define MEMROWS_ 64001L
#define TCH_ 5
#define NTCH_ (T_ / TCH_)   // 50

typedef __attribute__((ext_vector_type(8))) short bf16x8;
typedef __attribute__((ext_vector_type(4))) float f32x4;

__device__ __forceinline__ unsigned short f2bf(float x) {
    __hip_bfloat16 h = __float2bfloat16(x);
    return __builtin_bit_cast(unsigned short, h);
}
__device__ __forceinline__ float bf2f(unsigned short u) {
    __hip_bfloat16 h = __builtin_bit_cast(__hip_bfloat16, u);
    return __bfloat162float(h);
}

// tanh-form gelu: x * sigmoid(2*0.7978845608*(x + 0.044715 x^3)); max abs err vs exact ~5e-4
__device__ __forceinline__ float gelu_fast(float x) {
    float x2 = x * x;
    float m  = x * fmaf(x2, -0.0713555f, -1.5957691f);  // -2u
    float e  = __expf(m);
    return x * __builtin_amdgcn_rcpf(1.0f + e);
}

// ---- Stage 1: v-MLP. Wave->head, M-tile = 16 dh rows, K=cr(16, padded to 32), N=HID.
__global__ __launch_bounds__(256) void k_stage1(
    const float* __restrict__ mem, const float* __restrict__ dim_pe,
    const float* __restrict__ W1, const float* __restrict__ b1,
    const float* __restrict__ W2, const float* __restrict__ b2,
    unsigned short* __restrict__ vbuf)
{
    const int blk = blockIdx.x;                 // (b*CL + cl)*NTCH + tch
    const int tch = blk % NTCH_;
    const int cl  = (blk / NTCH_) % CL_;
    const int b   = blk / (NTCH_ * CL_);
    const int lane = threadIdx.x & 63;
    const int wv   = threadIdx.x >> 6;
    const int g  = lane >> 4;                   // k-group 0..3 (k = 8g+j)
    const int fl = lane & 15;
    const bool kact = (g < 2);                  // only k<16 is real

    const float* membase = mem + (long)b * MEMROWS_ * D_;
    unsigned short* vrow = vbuf + (long)(b * CL_ + cl) * T_ * D_;

#pragma unroll 1
    for (int jn = 0; jn < 4; ++jn) {
        const int nh = wv * 4 + jn;
        // W1 B-fragments: bfrag[cn][j] = W1[nh][k=8g+j][f=cn*16+fl]
        bf16x8 bfrag[4];
        float b1v[4], w2v[4];
#pragma unroll
        for (int cn = 0; cn < 4; ++cn) {
            bf16x8 bf = {0,0,0,0,0,0,0,0};
            if (kact) {
#pragma unroll
                for (int j = 0; j < 8; ++j) {
                    float w = W1[(nh * CRv_ + (8 * g + j)) * HID_ + cn * 16 + fl];
                    bf[j] = (short)f2bf(w);
                }
            }
            bfrag[cn] = bf;
            b1v[cn] = b1[nh * HID_ + cn * 16 + fl];
            w2v[cn] = W2[nh * HID_ + cn * 16 + fl];
        }
        const float b2s = b2[nh];

#pragma unroll 1
        for (int ct = 0; ct < 4; ++ct) {
            const int d0 = nh * DH_ + ct * 16 + fl;   // this lane's d column
            float pef[8];
            if (kact) {
#pragma unroll
                for (int j = 0; j < 8; ++j)
                    pef[j] = dim_pe[(8 * g + j) * D_ + d0];
            }
            float xv[8];
            if (kact) {
#pragma unroll
                for (int j = 0; j < 8; ++j)
                    xv[j] = membase[((long)(cl * CRv_ + 8 * g + j) * T_ + tch * TCH_) * D_ + d0];
            }
#pragma unroll 1
            for (int tt = 0; tt < TCH_; ++tt) {
                const int t = tch * TCH_ + tt;
                bf16x8 af = {0,0,0,0,0,0,0,0};
                if (kact) {
#pragma unroll
                    for (int j = 0; j < 8; ++j)
                        af[j] = (short)f2bf(xv[j] + pef[j]);
                }
                if (kact && (tt + 1 < TCH_)) {        // prefetch next t under epilogue
#pragma unroll
                    for (int j = 0; j < 8; ++j)
                        xv[j] = membase[((long)(cl * CRv_ + 8 * g + j) * T_ + (t + 1)) * D_ + d0];
                }
                f32x4 acc[4];
#pragma unroll
                for (int cn = 0; cn < 4; ++cn) {
                    f32x4 z = {0.f, 0.f, 0.f, 0.f};
                    acc[cn] = __builtin_amdgcn_mfma_f32_16x16x32_bf16(af, bfrag[cn], z, 0, 0, 0);
                }
                // epilogue: h = gelu(pre + b1), out[row] = sum_f h*W2  (rows 4g+r, col f=16cn+fl)
                float pr0 = 0.f, pr1 = 0.f, pr2 = 0.f, pr3 = 0.f;
#pragma unroll
                for (int cn = 0; cn < 4; ++cn) {
                    pr0 = fmaf(gelu_fast(acc[cn][0] + b1v[cn]), w2v[cn], pr0);
                    pr1 = fmaf(gelu_fast(acc[cn][1] + b1v[cn]), w2v[cn], pr1);
                    pr2 = fmaf(gelu_fast(acc[cn][2] + b1v[cn]), w2v[cn], pr2);
                    pr3 = fmaf(gelu_fast(acc[cn][3] + b1v[cn]), w2v[cn], pr3);
                }
#pragma unroll
                for (int mk = 1; mk <= 8; mk <<= 1) {
                    pr0 += __shfl_xor(pr0, mk);
                    pr1 += __shfl_xor(pr1, mk);
                    pr2 += __shfl_xor(pr2, mk);
                    pr3 += __shfl_xor(pr3, mk);
                }
                float o01 = (fl & 1) ? pr1 : pr0;
                float o23 = (fl & 1) ? pr3 : pr2;
                float ov  = ((fl & 2) ? o23 : o01) + b2s;
                if (fl < 4) {
                    const int dh = ct * 16 + 4 * g + fl;
                    vrow[(long)t * D_ + nh * DH_ + dh] = f2bf(ov);
                }
            }
        }
    }
}

// ---- Stage 2: h-MLP over t-within-chunk (K=cr via t=tc*16+cr, pad rows -> nonsense)
__global__ __launch_bounds__(256) void k_stage2(
    const unsigned short* __restrict__ vbuf, const float* __restrict__ mem,
    const float* __restrict__ W1, const float* __restrict__ b1,
    const float* __restrict__ W2, const float* __restrict__ b2,
    float* __restrict__ hbuf)
{
    const int blk = blockIdx.x;                // (((b*CL + cl)*16 + tc)*4 + nhg)
    const int nhg = blk & 3;
    const int tc  = (blk >> 2) & 15;
    const int cl  = (blk >> 6) & 15;
    const int b   = blk >> 10;
    const int lane = threadIdx.x & 63;
    const int wv   = threadIdx.x >> 6;
    const int g  = lane >> 4;
    const int fl = lane & 15;
    const bool kact = (g < 2);
    const int nh = nhg * 4 + wv;

    const unsigned short* vrow = vbuf + (long)(b * CL_ + cl) * T_ * D_;
    const float* nons = mem + ((long)b * MEMROWS_ + (long)L_ * T_) * D_;

    bf16x8 bfrag[4];
    float b1v[4], w2v[4];
#pragma unroll
    for (int cn = 0; cn < 4; ++cn) {
        bf16x8 bf = {0,0,0,0,0,0,0,0};
        if (kact) {
#pragma unroll
            for (int j = 0; j < 8; ++j) {
                float w = W1[(nh * CRv_ + (8 * g + j)) * HID_ + cn * 16 + fl];
                bf[j] = (short)f2bf(w);
            }
        }
        bfrag[cn] = bf;
        b1v[cn] = b1[nh * HID_ + cn * 16 + fl];
        w2v[cn] = W2[nh * HID_ + cn * 16 + fl];
    }
    const float b2s = b2[nh];

#pragma unroll 1
    for (int ct = 0; ct < 4; ++ct) {
        const int d0 = nh * DH_ + ct * 16 + fl;
        const float nv = nons[d0];
        bf16x8 af = {0,0,0,0,0,0,0,0};
        if (kact) {
#pragma unroll
            for (int j = 0; j < 8; ++j) {
                const int t = tc * CRv_ + 8 * g + j;
                float xv = (t < T_) ? bf2f(vrow[(long)t * D_ + d0]) : nv;
                af[j] = (short)f2bf(xv);
            }
        }
        f32x4 acc[4];
#pragma unroll
        for (int cn = 0; cn < 4; ++cn) {
            f32x4 z = {0.f, 0.f, 0.f, 0.f};
            acc[cn] = __builtin_amdgcn_mfma_f32_16x16x32_bf16(af, bfrag[cn], z, 0, 0, 0);
        }
        float pr0 = 0.f, pr1 = 0.f, pr2 = 0.f, pr3 = 0.f;
#pragma unroll
        for (int cn = 0; cn < 4; ++cn) {
            pr0 = fmaf(gelu_fast(acc[cn][0] + b1v[cn]), w2v[cn], pr0);
            pr1 = fmaf(gelu_fast(acc[cn][1] + b1v[cn]), w2v[cn], pr1);
            pr2 = fmaf(gelu_fast(acc[cn][2] + b1v[cn]), w2v[cn], pr2);
            pr3 = fmaf(gelu_fast(acc[cn][3] + b1v[cn]), w2v[cn], pr3);
        }
#pragma unroll
        for (int mk = 1; mk <= 8; mk <<= 1) {
            pr0 += __shfl_xor(pr0, mk);
            pr1 += __shfl_xor(pr1, mk);
            pr2 += __shfl_xor(pr2, mk);
            pr3 += __shfl_xor(pr3, mk);
        }
        float o01 = (fl & 1) ? pr1 : pr0;
        float o23 = (fl & 1) ? pr3 : pr2;
        float ov  = ((fl & 2) ? o23 : o01) + b2s;
        if (fl < 4) {
            const int dh = ct * 16 + 4 * g + fl;
            hbuf[(long)((b * CL_ + cl) * 16 + tc) * D_ + nh * DH_ + dh] = ov;
        }
    }
}

// ---- Stage 3: C(512x1024) = H @ projW^T + bias (fp32 tiled GEMM, unchanged)
__global__ __launch_bounds__(256) void k_proj(
    const float* __restrict__ H, const float* __restrict__ Wp,
    const float* __restrict__ bias, float* __restrict__ Cout)
{
    constexpr int BM = 32, BN = 64, BK = 32, K = 1024, NCOLB = OUT_ / BN; // 16
    __shared__ float Ht[BM][BK + 1];
    __shared__ float Wt[BN][BK + 1];

    const int bn = blockIdx.x % NCOLB;
    const int bm = blockIdx.x / NCOLB;
    const int tid = threadIdx.x;
    const int tx = tid & 15;
    const int ty = tid >> 4;
    const int lr = tid >> 3;
    const int lc = (tid & 7) << 2;

    float acc[2][4] = {};

    for (int k0 = 0; k0 < K; k0 += BK) {
        float4 hv  = *(const float4*)(H  + (long)(bm * BM + lr) * K + k0 + lc);
        float4 w0  = *(const float4*)(Wp + (long)(bn * BN + lr) * K + k0 + lc);
        float4 w1v = *(const float4*)(Wp + (long)(bn * BN + 32 + lr) * K + k0 + lc);
        Ht[lr][lc + 0] = hv.x;  Ht[lr][lc + 1] = hv.y;  Ht[lr][lc + 2] = hv.z;  Ht[lr][lc + 3] = hv.w;
        Wt[lr][lc + 0] = w0.x;  Wt[lr][lc + 1] = w0.y;  Wt[lr][lc + 2] = w0.z;  Wt[lr][lc + 3] = w0.w;
        Wt[32 + lr][lc + 0] = w1v.x; Wt[32 + lr][lc + 1] = w1v.y; Wt[32 + lr][lc + 2] = w1v.z; Wt[32 + lr][lc + 3] = w1v.w;
        __syncthreads();

#pragma unroll
        for (int kk = 0; kk < BK; ++kk) {
            float va0 = Ht[ty * 2 + 0][kk];
            float va1 = Ht[ty * 2 + 1][kk];
            float vb0 = Wt[tx * 4 + 0][kk];
            float vb1 = Wt[tx * 4 + 1][kk];
            float vb2 = Wt[tx * 4 + 2][kk];
            float vb3 = Wt[tx * 4 + 3][kk];
            acc[0][0] = fmaf(va0, vb0, acc[0][0]);
            acc[0][1] = fmaf(va0, vb1, acc[0][1]);
            acc[0][2] = fmaf(va0, vb2, acc[0][2]);
            acc[0][3] = fmaf(va0, vb3, acc[0][3]);
            acc[1][0] = fmaf(va1, vb0, acc[1][0]);
            acc[1][1] = fmaf(va1, vb1, acc[1][1]);
            acc[1][2] = fmaf(va1, vb2, acc[1][2]);
            acc[1][3] = fmaf(va1, vb3, acc[1][3]);
        }
        __syncthreads();
    }

#pragma unroll
    for (int i = 0; i < 2; ++i) {
#pragma unroll
        for (int jj = 0; jj < 4; ++jj) {
            int r = bm * BM + ty * 2 + i;
            int c = bn * BN + tx * 4 + jj;
            Cout[(long)r * OUT_ + c] = acc[i][jj] + bias[c];
        }
    }
}

extern "C" void kernel_launch(void* const* d_in, const int* in_sizes, int n_in,
                              void* d_out, int out_size, void* d_ws, size_t ws_size,
                              hipStream_t stream) {
    const float* mem    = (const float*)d_in[0];
    const float* dim_pe = (const float*)d_in[2];
    const float* vW1    = (const float*)d_in[3];
    const float* vb1    = (const float*)d_in[4];
    const float* vW2    = (const float*)d_in[5];
    const float* vb2    = (const float*)d_in[6];
    const float* hW1    = (const float*)d_in[7];
    const float* hb1    = (const float*)d_in[8];
    const float* hW2    = (const float*)d_in[9];
    const float* hb2    = (const float*)d_in[10];
    const float* projW  = (const float*)d_in[11];
    const float* projb  = (const float*)d_in[12];
    float* out = (float*)d_out;

    unsigned short* vbuf = (unsigned short*)d_ws;                       // 16,384,000 B (bf16)
    float* hbuf = (float*)((char*)d_ws + (size_t)B_ * CL_ * T_ * D_ * sizeof(unsigned short));

    k_stage1<<<B_ * CL_ * NTCH_, 256, 0, stream>>>(mem, dim_pe, vW1, vb1, vW2, vb2, vbuf);
    k_stage2<<<B_ * CL_ * 16 * 4, 256, 0, stream>>>(vbuf, mem, hW1, hb1, hW2, hb2, hbuf);
    k_proj<<<(512 / 32) * (OUT_ / 64), 256, 0, stream>>>(hbuf, projW, projb, out);
}

// Round 3
// 330.527 us; speedup vs baseline: 2.1162x; 1.2486x over previous
//
#include <hip/hip_runtime.h>
#include <hip/hip_bf16.h>

#define B_ 2
#define L_ 256
#define T_ 250
#define D_ 1024
#define NH_ 16
#define DH_ 64
#define CRv_ 16
#define HID_ 64
#define CL_ 16
#define OUT_ 1024
#define MEMROWS_ 64001L
#define TCH_ 10
#define NTCH_ (T_ / TCH_)   // 25

typedef __attribute__((ext_vector_type(8))) short bf16x8;
typedef __attribute__((ext_vector_type(4))) float f32x4;

__device__ __forceinline__ unsigned short f2bf(float x) {
    __hip_bfloat16 h = __float2bfloat16(x);
    return __builtin_bit_cast(unsigned short, h);
}
__device__ __forceinline__ float bf2f(unsigned short u) {
    __hip_bfloat16 h = __builtin_bit_cast(unsigned short, u) , *hp = &h; // avoid UB gymnastics
    return __bfloat162float(*hp);
}

__device__ __forceinline__ float exp2_fast(float x) {
#if __has_builtin(__builtin_amdgcn_exp2f)
    return __builtin_amdgcn_exp2f(x);
#else
    return __expf(x * 0.6931471805599453f);
#endif
}

// gelu(x) ~= x * sigmoid(1.5957691*(x + 0.044715 x^3)); exp2 form, log2e folded.
__device__ __forceinline__ float gelu_fast(float x) {
    float x2 = x * x;
    float z  = x * fmaf(x2, -0.1029445f, -2.3022055f);   // -(2u)*log2(e)
    float e  = exp2_fast(z);
    return x * __builtin_amdgcn_rcpf(1.0f + e);
}

// ---- Stage 1: v-MLP. One wave = one head. M=16 dh rows, K=cr(16 in 32), N=HID.
__global__ __launch_bounds__(256) void k_stage1(
    const float* __restrict__ mem, const float* __restrict__ dim_pe,
    const float* __restrict__ W1, const float* __restrict__ b1,
    const float* __restrict__ W2, const float* __restrict__ b2,
    unsigned short* __restrict__ vbuf)
{
    const int blk = blockIdx.x;                 // ((b*CL + cl)*NTCH + tch)*4 + nhg
    const int nhg  = blk & 3;
    const int tch  = (blk >> 2) % NTCH_;
    const int rest = (blk >> 2) / NTCH_;
    const int cl   = rest & (CL_ - 1);
    const int b    = rest >> 4;
    const int lane = threadIdx.x & 63;
    const int wv   = threadIdx.x >> 6;
    const int nh   = nhg * 4 + wv;
    const int g    = lane >> 4;                 // k-group: k = 8g + j (only g<2 real)
    const int fl   = lane & 15;
    const int kbase = (8 * g) & 15;             // clamped row base for dup loads
    const bool klive = (g < 2);

    const float* membase = mem + (long)b * MEMROWS_ * D_;
    unsigned short* vrow = vbuf + (long)(b * CL_ + cl) * T_ * D_;

    // Per-wave invariants: W1 B-fragments (upper K zeroed), b1, W2, b2.
    bf16x8 bfrag[4];
    float b1v[4], w2v[4];
#pragma unroll
    for (int cn = 0; cn < 4; ++cn) {
        bf16x8 bf;
#pragma unroll
        for (int j = 0; j < 8; ++j) {
            float w = W1[(nh * CRv_ + kbase + j) * HID_ + cn * 16 + fl];
            bf[j] = klive ? (short)f2bf(w) : (short)0;
        }
        bfrag[cn] = bf;
        b1v[cn] = b1[nh * HID_ + cn * 16 + fl];
        w2v[cn] = W2[nh * HID_ + cn * 16 + fl];
    }
    const float b2s = b2[nh];

#pragma unroll 1
    for (int ct = 0; ct < 4; ++ct) {
        const int d0 = nh * DH_ + ct * 16 + fl;

        float pef[8];
#pragma unroll
        for (int j = 0; j < 8; ++j)
            pef[j] = dim_pe[(kbase + j) * D_ + d0];

        const int t0 = tch * TCH_;
        float xv[8];
#pragma unroll
        for (int j = 0; j < 8; ++j)
            xv[j] = membase[((cl * CRv_ + kbase + j) * T_ + t0) * D_ + d0];

        for (int tt = 0; tt < TCH_; ++tt) {
            const int t = t0 + tt;
            bf16x8 af;
#pragma unroll
            for (int j = 0; j < 8; ++j)
                af[j] = (short)f2bf(xv[j] + pef[j]);

            if (tt + 1 < TCH_) {
#pragma unroll
                for (int j = 0; j < 8; ++j)
                    xv[j] = membase[((cl * CRv_ + kbase + j) * T_ + t + 1) * D_ + d0];
            }

            f32x4 acc[4];
#pragma unroll
            for (int cn = 0; cn < 4; ++cn) {
                f32x4 ci = {b1v[cn], b1v[cn], b1v[cn], b1v[cn]};
                acc[cn] = __builtin_amdgcn_mfma_f32_16x16x32_bf16(af, bfrag[cn], ci, 0, 0, 0);
            }

            float pr0 = 0.f, pr1 = 0.f, pr2 = 0.f, pr3 = 0.f;
#pragma unroll
            for (int cn = 0; cn < 4; ++cn) {
                pr0 = fmaf(gelu_fast(acc[cn][0]), w2v[cn], pr0);
                pr1 = fmaf(gelu_fast(acc[cn][1]), w2v[cn], pr1);
                pr2 = fmaf(gelu_fast(acc[cn][2]), w2v[cn], pr2);
                pr3 = fmaf(gelu_fast(acc[cn][3]), w2v[cn], pr3);
            }
#pragma unroll
            for (int mk = 1; mk <= 8; mk <<= 1) {
                pr0 += __shfl_xor(pr0, mk);
                pr1 += __shfl_xor(pr1, mk);
                pr2 += __shfl_xor(pr2, mk);
                pr3 += __shfl_xor(pr3, mk);
            }
            float o01 = (fl & 1) ? pr1 : pr0;
            float o23 = (fl & 1) ? pr3 : pr2;
            float ov  = ((fl & 2) ? o23 : o01) + b2s;
            if (fl < 4) {
                vrow[t * D_ + nh * DH_ + ct * 16 + 4 * g + fl] = f2bf(ov);
            }
        }
    }
}

// ---- Stage 2: h-MLP over t = tc*16+cr (pad rows -> nonsense). One wave = one head.
__global__ __launch_bounds__(256) void k_stage2(
    const unsigned short* __restrict__ vbuf, const float* __restrict__ mem,
    const float* __restrict__ W1, const float* __restrict__ b1,
    const float* __restrict__ W2, const float* __restrict__ b2,
    float* __restrict__ hbuf)
{
    const int blk = blockIdx.x;                // ((b*CL + cl)*16 + tc)*4 + nhg
    const int nhg = blk & 3;
    const int tc  = (blk >> 2) & 15;
    const int cl  = (blk >> 6) & 15;
    const int b   = blk >> 10;
    const int lane = threadIdx.x & 63;
    const int wv   = threadIdx.x >> 6;
    const int nh   = nhg * 4 + wv;
    const int g    = lane >> 4;
    const int fl   = lane & 15;
    const int kbase = (8 * g) & 15;
    const bool klive = (g < 2);

    const unsigned short* vrow = vbuf + (long)(b * CL_ + cl) * T_ * D_;
    const float* nons = mem + ((long)b * MEMROWS_ + (long)L_ * T_) * D_;

    bf16x8 bfrag[4];
    float b1v[4], w2v[4];
#pragma unroll
    for (int cn = 0; cn < 4; ++cn) {
        bf16x8 bf;
#pragma unroll
        for (int j = 0; j < 8; ++j) {
            float w = W1[(nh * CRv_ + kbase + j) * HID_ + cn * 16 + fl];
            bf[j] = klive ? (short)f2bf(w) : (short)0;
        }
        bfrag[cn] = bf;
        b1v[cn] = b1[nh * HID_ + cn * 16 + fl];
        w2v[cn] = W2[nh * HID_ + cn * 16 + fl];
    }
    const float b2s = b2[nh];

#pragma unroll 1
    for (int ct = 0; ct < 4; ++ct) {
        const int d0 = nh * DH_ + ct * 16 + fl;
        const unsigned short nvb = f2bf(nons[d0]);

        bf16x8 af;
#pragma unroll
        for (int j = 0; j < 8; ++j) {
            const int t  = tc * CRv_ + kbase + j;
            const int tcl = (t < T_) ? t : (T_ - 1);
            unsigned short us = vrow[tcl * D_ + d0];
            af[j] = (short)((t < T_) ? us : nvb);
        }

        f32x4 acc[4];
#pragma unroll
        for (int cn = 0; cn < 4; ++cn) {
            f32x4 ci = {b1v[cn], b1v[cn], b1v[cn], b1v[cn]};
            acc[cn] = __builtin_amdgcn_mfma_f32_16x16x32_bf16(af, bfrag[cn], ci, 0, 0, 0);
        }

        float pr0 = 0.f, pr1 = 0.f, pr2 = 0.f, pr3 = 0.f;
#pragma unroll
        for (int cn = 0; cn < 4; ++cn) {
            pr0 = fmaf(gelu_fast(acc[cn][0]), w2v[cn], pr0);
            pr1 = fmaf(gelu_fast(acc[cn][1]), w2v[cn], pr1);
            pr2 = fmaf(gelu_fast(acc[cn][2]), w2v[cn], pr2);
            pr3 = fmaf(gelu_fast(acc[cn][3]), w2v[cn], pr3);
        }
#pragma unroll
        for (int mk = 1; mk <= 8; mk <<= 1) {
            pr0 += __shfl_xor(pr0, mk);
            pr1 += __shfl_xor(pr1, mk);
            pr2 += __shfl_xor(pr2, mk);
            pr3 += __shfl_xor(pr3, mk);
        }
        float o01 = (fl & 1) ? pr1 : pr0;
        float o23 = (fl & 1) ? pr3 : pr2;
        float ov  = ((fl & 2) ? o23 : o01) + b2s;
        if (fl < 4) {
            hbuf[(long)((b * CL_ + cl) * 16 + tc) * D_ + nh * DH_ + ct * 16 + 4 * g + fl] = ov;
        }
    }
}

// ---- Stage 3: C(512x1024) = H @ projW^T + bias (fp32 tiled GEMM)
__global__ __launch_bounds__(256) void k_proj(
    const float* __restrict__ H, const float* __restrict__ Wp,
    const float* __restrict__ bias, float* __restrict__ Cout)
{
    constexpr int BM = 32, BN = 64, BK = 32, K = 1024, NCOLB = OUT_ / BN; // 16
    __shared__ float Ht[BM][BK + 1];
    __shared__ float Wt[BN][BK + 1];

    const int bn = blockIdx.x % NCOLB;
    const int bm = blockIdx.x / NCOLB;
    const int tid = threadIdx.x;
    const int tx = tid & 15;
    const int ty = tid >> 4;
    const int lr = tid >> 3;
    const int lc = (tid & 7) << 2;

    float acc[2][4] = {};

    for (int k0 = 0; k0 < K; k0 += BK) {
        float4 hv  = *(const float4*)(H  + (long)(bm * BM + lr) * K + k0 + lc);
        float4 w0  = *(const float4*)(Wp + (long)(bn * BN + lr) * K + k0 + lc);
        float4 w1v = *(const float4*)(Wp + (long)(bn * BN + 32 + lr) * K + k0 + lc);
        Ht[lr][lc + 0] = hv.x;  Ht[lr][lc + 1] = hv.y;  Ht[lr][lc + 2] = hv.z;  Ht[lr][lc + 3] = hv.w;
        Wt[lr][lc + 0] = w0.x;  Wt[lr][lc + 1] = w0.y;  Wt[lr][lc + 2] = w0.z;  Wt[lr][lc + 3] = w0.w;
        Wt[32 + lr][lc + 0] = w1v.x; Wt[32 + lr][lc + 1] = w1v.y; Wt[32 + lr][lc + 2] = w1v.z; Wt[32 + lr][lc + 3] = w1v.w;
        __syncthreads();

#pragma unroll
        for (int kk = 0; kk < BK; ++kk) {
            float va0 = Ht[ty * 2 + 0][kk];
            float va1 = Ht[ty * 2 + 1][kk];
            float vb0 = Wt[tx * 4 + 0][kk];
            float vb1 = Wt[tx * 4 + 1][kk];
            float vb2 = Wt[tx * 4 + 2][kk];
            float vb3 = Wt[tx * 4 + 3][kk];
            acc[0][0] = fmaf(va0, vb0, acc[0][0]);
            acc[0][1] = fmaf(va0, vb1, acc[0][1]);
            acc[0][2] = fmaf(va0, vb2, acc[0][2]);
            acc[0][3] = fmaf(va0, vb3, acc[0][3]);
            acc[1][0] = fmaf(va1, vb0, acc[1][0]);
            acc[1][1] = fmaf(va1, vb1, acc[1][1]);
            acc[1][2] = fmaf(va1, vb2, acc[1][2]);
            acc[1][3] = fmaf(va1, vb3, acc[1][3]);
        }
        __syncthreads();
    }

#pragma unroll
    for (int i = 0; i < 2; ++i) {
#pragma unroll
        for (int jj = 0; jj < 4; ++jj) {
            int r = bm * BM + ty * 2 + i;
            int c = bn * BN + tx * 4 + jj;
            Cout[(long)r * OUT_ + c] = acc[i][jj] + bias[c];
        }
    }
}

extern "C" void kernel_launch(void* const* d_in, const int* in_sizes, int n_in,
                              void* d_out, int out_size, void* d_ws, size_t ws_size,
                              hipStream_t stream) {
    const float* mem    = (const float*)d_in[0];
    const float* dim_pe = (const float*)d_in[2];
    const float* vW1    = (const float*)d_in[3];
    const float* vb1    = (const float*)d_in[4];
    const float* vW2    = (const float*)d_in[5];
    const float* vb2    = (const float*)d_in[6];
    const float* hW1    = (const float*)d_in[7];
    const float* hb1    = (const float*)d_in[8];
    const float* hW2    = (const float*)d_in[9];
    const float* hb2    = (const float*)d_in[10];
    const float* projW  = (const float*)d_in[11];
    const float* projb  = (const float*)d_in[12];
    float* out = (float*)d_out;

    unsigned short* vbuf = (unsigned short*)d_ws;                       // bf16, 16 MB
    float* hbuf = (float*)((char*)d_ws + (size_t)B_ * CL_ * T_ * D_ * sizeof(unsigned short));

    k_stage1<<<B_ * CL_ * NTCH_ * 4, 256, 0, stream>>>(mem, dim_pe, vW1, vb1, vW2, vb2, vbuf);
    k_stage2<<<B_ * CL_ * 16 * 4, 256, 0, stream>>>(vbuf, mem, hW1, hb1, hW2, hb2, hbuf);
    k_proj<<<(512 / 32) * (OUT_ / 64), 256, 0, stream>>>(hbuf, projW, projb, out);
}